// Round 4
// baseline (225.544 us; speedup 1.0000x reference)
//
#include <hip/hip_runtime.h>

typedef __attribute__((ext_vector_type(8))) short bf16x8;
typedef __attribute__((ext_vector_type(4))) short bf16x4;
typedef __attribute__((ext_vector_type(4))) float f32x4;
typedef __attribute__((ext_vector_type(16))) float f32x16;

#define MFMA16(a,b,c) __builtin_amdgcn_mfma_f32_16x16x32_bf16((a),(b),(c),0,0,0)
#define MFMA32(a,b,c) __builtin_amdgcn_mfma_f32_32x32x16_bf16((a),(b),(c),0,0,0)

__device__ __forceinline__ short f2bf(float f) {
  union { float f; unsigned u; } v; v.f = f;
  unsigned r = v.u + 0x7FFFu + ((v.u >> 16) & 1u);   // RNE
  return (short)(r >> 16);
}
__device__ __forceinline__ float bf2f(short s) {
  union { unsigned u; float f; } v; v.u = ((unsigned)(unsigned short)s) << 16;
  return v.f;
}
__device__ __forceinline__ unsigned cvtpk(float lo, float hi) {
  unsigned d;
  asm("v_cvt_pk_bf16_f32 %0, %1, %2" : "=v"(d) : "v"(lo), "v"(hi));
  return d;
}
__device__ __forceinline__ void async16(const void* g, void* l) {
  __builtin_amdgcn_global_load_lds(
      (const __attribute__((address_space(1))) unsigned*)g,
      (__attribute__((address_space(3))) unsigned*)l, 16, 0, 0);
}

// ------------- convert Wq/Wk/Wv fp32 -> bf16 [3][256][256] -------------
__global__ void cvt_w_kernel(const float* __restrict__ Wq, const float* __restrict__ Wk,
                             const float* __restrict__ Wv, short* __restrict__ Wb) {
  int v = blockIdx.x * 256 + threadIdx.x;        // 24576 units of 8 elems
  int z = v >> 13, r = v & 8191;
  const float* src = ((z == 0) ? Wq : (z == 1) ? Wk : Wv) + r * 8;
  float4 a = *(const float4*)src;
  float4 b = *(const float4*)(src + 4);
  bf16x8 h;
  h[0]=f2bf(a.x); h[1]=f2bf(a.y); h[2]=f2bf(a.z); h[3]=f2bf(a.w);
  h[4]=f2bf(b.x); h[5]=f2bf(b.y); h[6]=f2bf(b.z); h[7]=f2bf(b.w);
  *(bf16x8*)(Wb + z * 65536 + r * 8) = h;
}

// ------------- proj: grid 768 = 256 mtiles x 3 z; BM=64; vectorized stores -------------
__global__ __launch_bounds__(256, 2) void proj_kernel(
    const float* __restrict__ x, const short* __restrict__ Wb,
    const float* __restrict__ bq, const float* __restrict__ bk, const float* __restrict__ bv,
    short* __restrict__ Qb, short* __restrict__ Kb, short* __restrict__ VTb)
{
  __shared__ __attribute__((aligned(16))) char xs[32768]; // x tile [64][256] bf16, swizzled
  const int tid = threadIdx.x;
  const int lane = tid & 63;
  const int w = tid >> 6;
  const int l15 = lane & 15, lg = lane >> 4;
  const int z = blockIdx.x >> 8;
  const int mtile = blockIdx.x & 255;
  const int m0 = mtile * 64;
  const int batch = m0 >> 12;
  const int s0 = m0 & 4095;

  // stage x[m0..+64][256] fp32 -> bf16 LDS; full-bijective swizzle u^(row&31)
  #pragma unroll
  for (int c = 0; c < 8; ++c) {
    int v = c * 256 + tid;          // 2048 16B-units, 32 units/row
    int row = v >> 5, u = v & 31;
    const float* g = x + (size_t)(m0 + row) * 256 + u * 8;
    float4 a = *(const float4*)g;
    float4 b = *(const float4*)(g + 4);
    bf16x8 h;
    h[0]=f2bf(a.x); h[1]=f2bf(a.y); h[2]=f2bf(a.z); h[3]=f2bf(a.w);
    h[4]=f2bf(b.x); h[5]=f2bf(b.y); h[6]=f2bf(b.z); h[7]=f2bf(b.w);
    *(bf16x8*)(xs + row * 512 + ((u ^ (row & 31)) * 16)) = h;
  }
  __syncthreads();

  const short* Wz = Wb + z * 65536;
  bf16x8 wf[4][8];
  #pragma unroll
  for (int fc = 0; fc < 4; ++fc)
    #pragma unroll
    for (int ks = 0; ks < 8; ++ks)
      wf[fc][ks] = *(const bf16x8*)(Wz + (size_t)(w*64 + fc*16 + l15) * 256 + ks*32 + lg*8);

  if (z < 2) {
    const float* bias = z ? bk : bq;
    short* Ob = z ? Kb : Qb;
    const float scl = z ? 1.0f : 0.0625f;
    float bb[4][4];
    #pragma unroll
    for (int fc = 0; fc < 4; ++fc)
      #pragma unroll
      for (int r = 0; r < 4; ++r) bb[fc][r] = bias[w*64 + fc*16 + lg*4 + r];
    #pragma unroll
    for (int ms = 0; ms < 4; ++ms) {
      bf16x8 xa[8];
      #pragma unroll
      for (int ks = 0; ks < 8; ++ks) {
        int row = ms * 16 + l15;
        xa[ks] = *(const bf16x8*)(xs + row * 512 + (((ks*4 + lg) ^ (row & 31)) * 16));
      }
      f32x4 acc[4];
      #pragma unroll
      for (int fc = 0; fc < 4; ++fc) acc[fc] = (f32x4){0.f,0.f,0.f,0.f};
      #pragma unroll
      for (int ks = 0; ks < 8; ++ks)
        #pragma unroll
        for (int fc = 0; fc < 4; ++fc)
          acc[fc] = MFMA16(wf[fc][ks], xa[ks], acc[fc]);   // D[e][m]: lane=m, regs=4 e
      #pragma unroll
      for (int fc = 0; fc < 4; ++fc) {
        bf16x4 pv;
        #pragma unroll
        for (int r = 0; r < 4; ++r) pv[r] = f2bf((acc[fc][r] + bb[fc][r]) * scl);
        *(bf16x4*)(Ob + (size_t)(m0 + ms*16 + l15) * 256 + w*64 + fc*16 + lg*4) = pv;
      }
    }
  } else {
    float bvr[4];
    #pragma unroll
    for (int fc = 0; fc < 4; ++fc) bvr[fc] = bv[w*64 + fc*16 + l15];
    #pragma unroll
    for (int ms = 0; ms < 4; ++ms) {
      bf16x8 xa[8];
      #pragma unroll
      for (int ks = 0; ks < 8; ++ks) {
        int row = ms * 16 + l15;
        xa[ks] = *(const bf16x8*)(xs + row * 512 + (((ks*4 + lg) ^ (row & 31)) * 16));
      }
      f32x4 acc[4];
      #pragma unroll
      for (int fc = 0; fc < 4; ++fc) acc[fc] = (f32x4){0.f,0.f,0.f,0.f};
      #pragma unroll
      for (int ks = 0; ks < 8; ++ks)
        #pragma unroll
        for (int fc = 0; fc < 4; ++fc)
          acc[fc] = MFMA16(xa[ks], wf[fc][ks], acc[fc]);   // D[s][e]: lane=e, regs=4 s
      #pragma unroll
      for (int fc = 0; fc < 4; ++fc) {
        bf16x4 pv;
        #pragma unroll
        for (int r = 0; r < 4; ++r) pv[r] = f2bf(acc[fc][r] + bvr[fc]);
        *(bf16x4*)(VTb + (size_t)(batch*256 + w*64 + fc*16 + l15) * 4096 + s0 + ms*16 + lg*4) = pv;
      }
    }
  }
}

// ------------- flash attention: 8 waves x 32q (BM=256), BN=32, NS=4 kv-split,
// ------------- 4-buffer LDS pipeline with COUNTED vmcnt (never drained mid-loop)
__global__ __launch_bounds__(512, 2) void attn_kernel(
    const short* __restrict__ Qb, const short* __restrict__ Kb,
    const short* __restrict__ VTb, short* __restrict__ Op, float* __restrict__ mlg)
{
  // 4 bufs x [K 16KB | V 16KB] = 128KB
  __shared__ __attribute__((aligned(16))) char smem[131072];
  const int tid = threadIdx.x;
  const int lane = tid & 63;
  const int w = tid >> 6;
  const int l31 = lane & 31, hi = lane >> 5;

  const int b = blockIdx.x;
  const int c = b & 15;                  // (batch, ns) combo; xcd = c&7
  const int batch = c >> 2, ns = c & 3;
  const int qt = b >> 4;                 // 0..15
  const int q0 = qt * 256;
  const int kvbase = ns * 1024;

  const char* Kg = (const char*)(Kb  + (size_t)batch * 4096 * 256);
  const char* Vg = (const char*)(VTb + (size_t)batch * 256 * 4096);

  bf16x8 qf[16];
  {
    const short* qrow = Qb + (size_t)(batch*4096 + q0 + w*32 + l31) * 256;
    #pragma unroll
    for (int ks = 0; ks < 16; ++ks) qf[ks] = *(const bf16x8*)(qrow + ks*16 + hi*8);
  }

  f32x16 o[8];
  #pragma unroll
  for (int i = 0; i < 8; ++i)
    #pragma unroll
    for (int r = 0; r < 16; ++r) o[i][r] = 0.f;
  float m_run = -1e30f, l_run = 0.f;

  auto stage = [&](int buf, int kv0) {
    char* kl = smem + buf * 32768;
    #pragma unroll
    for (int cc = 0; cc < 2; ++cc) {
      int v = cc * 512 + tid;           // 1024 units: 32 rows x 32 units
      int row = v >> 5, s = v & 31;
      async16(Kg + (size_t)(kvbase ? 0 : 0) + (size_t)(kv0 + row) * 512 + ((s ^ row) * 16),
              kl + (size_t)v * 16);
    }
    char* vl = smem + buf * 32768 + 16384;
    #pragma unroll
    for (int cc = 0; cc < 2; ++cc) {
      int v = cc * 512 + tid;           // 1024 units: 32 super-rows (8 d) x 32 units
      int sr = v >> 5, j = v & 31;
      int jun = j ^ sr;
      int d = sr * 8 + (jun >> 2), u = jun & 3;
      async16(Vg + (size_t)d * 8192 + (size_t)kv0 * 2 + u * 16,
              vl + (size_t)v * 16);
    }
  };

  stage(0, kvbase);
  stage(1, kvbase + 32);
  stage(2, kvbase + 64);

  for (int t = 0; t < 32; ++t) {
    if (t < 30)       asm volatile("s_waitcnt vmcnt(8)" ::: "memory");
    else if (t == 30) asm volatile("s_waitcnt vmcnt(4)" ::: "memory");
    else              asm volatile("s_waitcnt vmcnt(0)" ::: "memory");
    __builtin_amdgcn_sched_barrier(0);
    __builtin_amdgcn_s_barrier();
    __builtin_amdgcn_sched_barrier(0);
    if (t < 29) stage((t + 3) & 3, kvbase + (t + 3) * 32);

    const char* kl = smem + (t & 3) * 32768;
    const char* vl = kl + 16384;

    // QK^T swapped: st = S^T[kv = (r&3)+8*(r>>2)+4*hi][q = l31]
    f32x16 st;
    #pragma unroll
    for (int r = 0; r < 16; ++r) st[r] = 0.f;
    __builtin_amdgcn_s_setprio(1);
    #pragma unroll
    for (int ks = 0; ks < 16; ++ks) {
      bf16x8 kf = *(const bf16x8*)(kl + l31 * 512 + (((ks*2 + hi) ^ l31) * 16));
      st = MFMA32(kf, qf[ks], st);
    }
    __builtin_amdgcn_s_setprio(0);

    // online softmax (per q = l31, across hi pair via shfl)
    float mx = st[0];
    #pragma unroll
    for (int r = 1; r < 16; ++r) mx = fmaxf(mx, st[r]);
    mx = fmaxf(mx, __shfl_xor(mx, 32));
    float m_new = fmaxf(m_run, mx);
    if (m_new > m_run) {
      float alpha = __expf(m_run - m_new);
      l_run *= alpha;
      #pragma unroll
      for (int df = 0; df < 8; ++df) o[df] = o[df] * alpha;
      m_run = m_new;
    }
    float lsum = 0.f;
    #pragma unroll
    for (int r = 0; r < 16; ++r) { st[r] = __expf(st[r] - m_run); lsum += st[r]; }
    l_run += lsum;

    // pack P to B-frags in-register (cvt_pk + shfl_xor32 + select)
    bf16x8 pa[2];
    #pragma unroll
    for (int kvf = 0; kvf < 2; ++kvf) {
      unsigned X  = cvtpk(st[8*kvf+0], st[8*kvf+1]);
      unsigned X2 = cvtpk(st[8*kvf+2], st[8*kvf+3]);
      unsigned Y  = cvtpk(st[8*kvf+4], st[8*kvf+5]);
      unsigned Y2 = cvtpk(st[8*kvf+6], st[8*kvf+7]);
      unsigned Xs  = __shfl_xor((int)X, 32);
      unsigned X2s = __shfl_xor((int)X2, 32);
      unsigned Ys  = __shfl_xor((int)Y, 32);
      unsigned Y2s = __shfl_xor((int)Y2, 32);
      union { unsigned u[4]; bf16x8 v; } fr;
      fr.u[0] = hi ? Ys  : X;
      fr.u[1] = hi ? Y2s : X2;
      fr.u[2] = hi ? Y   : Xs;
      fr.u[3] = hi ? Y2  : X2s;
      pa[kvf] = fr.v;
    }

    // PV: O^T[d][q] += V-frag(A, m=d) x P-frag(B, n=q); full d=256
    __builtin_amdgcn_s_setprio(1);
    #pragma unroll
    for (int kvf = 0; kvf < 2; ++kvf) {
      #pragma unroll
      for (int df = 0; df < 8; ++df) {
        int sr = df * 4 + (l31 >> 3);
        int j = ((l31 & 7) * 4 + kvf * 2 + hi) ^ sr;
        bf16x8 vb = *(const bf16x8*)(vl + sr * 512 + j * 16);
        o[df] = MFMA32(vb, pa[kvf], o[df]);
      }
    }
    __builtin_amdgcn_s_setprio(0);
  }

  // ---- epilogue: per-wave partial, no cross-wave merge needed ----
  float lt = l_run + __shfl_xor(l_run, 32);
  const int qglob = batch*4096 + q0 + w*32 + l31;
  short* op = Op + ((size_t)ns * 16384 + qglob) * 256;
  #pragma unroll
  for (int df = 0; df < 8; ++df)
    #pragma unroll
    for (int g = 0; g < 4; ++g) {
      bf16x4 pv;
      #pragma unroll
      for (int cc = 0; cc < 4; ++cc) pv[cc] = f2bf(o[df][4*g + cc]);
      *(bf16x4*)(op + df*32 + 8*g + 4*hi) = pv;
    }
  if (!hi) {
    mlg[((size_t)ns*16384 + qglob)*2]     = m_run;
    mlg[((size_t)ns*16384 + qglob)*2 + 1] = lt;
  }
}

// ------------- combine the four kv-split partials (bf16 in, fp32 out) -------------
__global__ void combine_kernel(const short* __restrict__ Op, const float* __restrict__ mlg,
                               float* __restrict__ out) {
  int idx = blockIdx.x * 256 + threadIdx.x;     // 524288 = 16384 rows x 32 chunks
  int row = idx >> 5, c = idx & 31;
  float m[4], l[4];
  #pragma unroll
  for (int p = 0; p < 4; ++p) {
    m[p] = mlg[((size_t)p*16384 + row)*2];
    l[p] = mlg[((size_t)p*16384 + row)*2 + 1];
  }
  float ms = fmaxf(fmaxf(m[0], m[1]), fmaxf(m[2], m[3]));
  float a[4], den = 0.f;
  #pragma unroll
  for (int p = 0; p < 4; ++p) { a[p] = __expf(m[p] - ms); den += a[p]*l[p]; }
  float inv = 1.0f / den;
  float acc[8];
  #pragma unroll
  for (int j = 0; j < 8; ++j) acc[j] = 0.f;
  #pragma unroll
  for (int p = 0; p < 4; ++p) {
    bf16x8 v = *(const bf16x8*)(Op + ((size_t)p*16384 + row)*256 + c*8);
    #pragma unroll
    for (int j = 0; j < 8; ++j) acc[j] += a[p] * bf2f(v[j]);
  }
  float4 r0 = {acc[0]*inv, acc[1]*inv, acc[2]*inv, acc[3]*inv};
  float4 r1 = {acc[4]*inv, acc[5]*inv, acc[6]*inv, acc[7]*inv};
  float* po = out + (size_t)row * 256 + c * 8;
  *(float4*)po = r0;
  *(float4*)(po + 4) = r1;
}

extern "C" void kernel_launch(void* const* d_in, const int* in_sizes, int n_in,
                              void* d_out, int out_size, void* d_ws, size_t ws_size,
                              hipStream_t stream) {
  const float* x  = (const float*)d_in[0];
  const float* Wq = (const float*)d_in[1];
  const float* bq = (const float*)d_in[2];
  const float* Wk = (const float*)d_in[3];
  const float* bk = (const float*)d_in[4];
  const float* Wv = (const float*)d_in[5];
  const float* bv = (const float*)d_in[6];
  float* out = (float*)d_out;

  char* ws = (char*)d_ws;
  short* Qb  = (short*)(ws);                         // 8 MiB  [16384][256] bf16 (1/16 folded)
  short* Kb  = (short*)(ws + 8388608);               // 8 MiB  [16384][256] bf16
  short* VTb = (short*)(ws + 16777216);              // 8 MiB  [4][256][4096] bf16
  short* Wb  = (short*)(ws + 25165824);              // 384 KiB [3][256][256] bf16
  float* mlg = (float*)(ws + 25559040);              // 512 KiB [4][16384][2] f32
  short* Op  = (short*)(ws + 26083328);              // 32 MiB [4][16384][256] bf16

  cvt_w_kernel<<<dim3(96), dim3(256), 0, stream>>>(Wq, Wk, Wv, Wb);
  proj_kernel<<<dim3(768), dim3(256), 0, stream>>>(x, Wb, bq, bk, bv, Qb, Kb, VTb);
  attn_kernel<<<dim3(256), dim3(512), 0, stream>>>(Qb, Kb, VTb, Op, mlg);
  combine_kernel<<<dim3(2048), dim3(256), 0, stream>>>(Op, mlg, out);
}